// Round 5
// baseline (200.657 us; speedup 1.0000x reference)
//
#include <hip/hip_runtime.h>
#include <stdint.h>

// SupConLossWithPrototype on MI355X.
// Round 16: remainder after k_sym is 69us and k_final is the heavy part
// (512 blocks x redundant proto staging+conversion). Changes:
//  - proto GEMM moved into k_sym's 64 diagonal blocks (they already hold the
//    A-fragments for their 128 rows); protos staged into the reused B-LDS
//    buffer once per diag block (64x conversion instead of 512x). Emits
//    Psum/expPsum/PLab/nf per row. Hidden under the 992 pair blocks.
//  - k_final collapses to 64 blocks x 128 thr: per row 128 coalesced slot
//    loads + scalar math + 1 atomic/block.
//  - k_sym inner loop: cross-quad shfl(16/32)+LDS store per ct deferred to
//    a single post-loop reduction (statically-indexed cp registers).

#define M_TOT 8192
#define K_DIM 128
#define B_PRO 100
#define INV_T 5.0f                          // 1/TEMP
#define C_SCALE 7.2134752044448170f         // 5 * log2(e)
#define LN2    0.6931471805599453f
#define RT    256                           // k_sym tile side
#define NT    (M_TOT / RT)                  // 32 row/col groups
#define NDIAG (2 * NT)                      // 64 diagonal half-blocks
#define NPAIR (NT * (NT - 1) / 2)           // 496 strict upper pairs
#define NBLK  (NDIAG + 2 * NPAIR)           // 1056 blocks
#define BS    136                           // B/proto LDS stride (bf16 elems)
#define PB    112                           // padded proto rows (7 groups of 16)

#if __has_builtin(__builtin_amdgcn_exp2f)
#define EXP2(x) __builtin_amdgcn_exp2f(x)
#else
#define EXP2(x) __expf((x) * 0.6931471805599453f)
#endif

typedef __attribute__((ext_vector_type(8))) short  short8;   // 8 bf16 (MFMA A/B frag)
typedef __attribute__((ext_vector_type(4))) float  floatx4;  // MFMA C/D frag

__device__ __forceinline__ float bf2f(unsigned short u) {
    union { unsigned int i; float f; } v; v.i = ((unsigned int)u) << 16; return v.f;
}
__device__ __forceinline__ unsigned short f2bf(float x) {   // RNE
    union { float f; unsigned int i; } v; v.f = x;
    return (unsigned short)((v.i + 0x7fffu + ((v.i >> 16) & 1u)) >> 16);
}
__device__ __forceinline__ short8 pack8(float4 a, float4 b, float sc) {
    short8 r;
    r[0] = (short)f2bf(a.x * sc); r[1] = (short)f2bf(a.y * sc);
    r[2] = (short)f2bf(a.z * sc); r[3] = (short)f2bf(a.w * sc);
    r[4] = (short)f2bf(b.x * sc); r[5] = (short)f2bf(b.y * sc);
    r[6] = (short)f2bf(b.z * sc); r[7] = (short)f2bf(b.w * sc);
    return r;
}

// ---------------------------------------------------------------- k_sym body
// One 128-row x 256-col half-tile, operands converted in-block from f32 feat.
// Dual accumulation: accE = sum exp2(D)*mask, accS = sum D*mask, row and col
// direction. DIAG excludes row==col exactly, and afterwards reuses ldsB for
// the proto tile to compute P = feat.protos^T/T for its 128 rows (MFMA),
// emitting Psum/expPsum/PLab/nf. Pair blocks zero complementary row-slots.
template<bool DIAG>
__device__ __forceinline__ void sym_body(
        int a, int b, int h, int R0, int C0,
        const float* __restrict__ feat, const int* __restrict__ labels,
        const float* __restrict__ protos, const int* __restrict__ plabels,
        float* __restrict__ rowE, float* __restrict__ rowS,
        int* __restrict__ nfpart, int* __restrict__ nf,
        float* __restrict__ Psum, float* __restrict__ expPsum,
        float* __restrict__ PLab,
        unsigned short* ldsB, float (*colE)[256], float (*colS)[256],
        float* novR, float* novC, int* plabL, int* labRow) {
    const int tid = threadIdx.x;
    const int wv = tid >> 6, lane = tid & 63;
    const int quad = lane >> 4, cq = lane & 15;

    if (tid < B_PRO) plabL[tid] = plabels[tid];

    // A fragments straight from f32 feat, converted in registers:
    // rows R0 + wv*32 + mt*16 + cq, k = ks*32 + quad*8 .. +7
    short8 afr[2][4];
    #pragma unroll
    for (int mt = 0; mt < 2; ++mt)
        #pragma unroll
        for (int ks = 0; ks < 4; ++ks) {
            const float* s = feat + (size_t)(R0 + wv * 32 + mt * 16 + cq) * K_DIM
                             + ks * 32 + quad * 8;
            float4 x = ((const float4*)s)[0];
            float4 y = ((const float4*)s)[1];
            afr[mt][ks] = pack8(x, y, 1.0f);
        }
    __syncthreads();   // plabL visible

    // novelty for 128 rows + 256 cols from labels x plabels (+labRow capture)
    for (int e = tid; e < 384; e += 256) {
        const int g = (e < 128) ? (R0 + e) : (C0 + (e - 128));
        const int lbl = labels[g];
        int m = 0;
        #pragma unroll 4
        for (int j = 0; j < B_PRO; ++j) m |= (plabL[j] == lbl);
        const float nv = m ? 0.f : 1.f;
        if (e < 128) { novR[e] = nv; labRow[e] = lbl; }
        else novC[e - 128] = nv;
    }
    __syncthreads();   // novR/novC visible

    float nmR[2][4];
    #pragma unroll
    for (int mt = 0; mt < 2; ++mt)
        #pragma unroll
        for (int r = 0; r < 4; ++r)
            nmR[mt][r] = novR[wv * 32 + mt * 16 + quad * 4 + r];
    float nmcA[16];
    #pragma unroll
    for (int c2 = 0; c2 < 16; ++c2)
        nmcA[c2] = novC[c2 * 16 + cq];

    float accE[2][4], accS[2][4];
    #pragma unroll
    for (int mt = 0; mt < 2; ++mt)
        #pragma unroll
        for (int r = 0; r < 4; ++r) { accE[mt][r] = 0.f; accS[mt][r] = 0.f; }
    float cpE_[2][8], cpS_[2][8];   // deferred col partials (static idx only)
    #pragma unroll
    for (int hh = 0; hh < 2; ++hh)
        #pragma unroll
        for (int cc = 0; cc < 8; ++cc) { cpE_[hh][cc] = 0.f; cpS_[hh][cc] = 0.f; }

    const int rbase = R0 + wv * 32 + quad * 4;   // DIAG row index helper

    #pragma unroll
    for (int half = 0; half < 2; ++half) {
        // stage cols [C0 + half*128, +128) as bf16(C*f) into LDS
        for (int e = tid; e < 2048; e += 256) {
            const int col = e >> 4, sg = e & 15;
            const float* s = feat + (size_t)(C0 + half * 128 + col) * K_DIM + sg * 8;
            float4 x = ((const float4*)s)[0];
            float4 y = ((const float4*)s)[1];
            ushort4 o0 = make_ushort4(f2bf(x.x*C_SCALE), f2bf(x.y*C_SCALE),
                                      f2bf(x.z*C_SCALE), f2bf(x.w*C_SCALE));
            ushort4 o1 = make_ushort4(f2bf(y.x*C_SCALE), f2bf(y.y*C_SCALE),
                                      f2bf(y.z*C_SCALE), f2bf(y.w*C_SCALE));
            *(ushort4*)&ldsB[col * BS + sg * 8]     = o0;
            *(ushort4*)&ldsB[col * BS + sg * 8 + 4] = o1;
        }
        __syncthreads();   // staging visible

        #pragma unroll
        for (int ct8 = 0; ct8 < 8; ++ct8) {
            const int ct = half * 8 + ct8;
            const unsigned short* bp = &ldsB[(ct8 * 16 + cq) * BS + quad * 8];
            short8 b0 = *(const short8*)(bp);
            short8 b1 = *(const short8*)(bp + 32);
            short8 b2 = *(const short8*)(bp + 64);
            short8 b3 = *(const short8*)(bp + 96);

            floatx4 D0 = (floatx4){0.f, 0.f, 0.f, 0.f};
            floatx4 D1 = (floatx4){0.f, 0.f, 0.f, 0.f};
            D0 = __builtin_amdgcn_mfma_f32_16x16x32_bf16(afr[0][0], b0, D0, 0, 0, 0);
            D0 = __builtin_amdgcn_mfma_f32_16x16x32_bf16(afr[0][1], b1, D0, 0, 0, 0);
            D0 = __builtin_amdgcn_mfma_f32_16x16x32_bf16(afr[0][2], b2, D0, 0, 0, 0);
            D0 = __builtin_amdgcn_mfma_f32_16x16x32_bf16(afr[0][3], b3, D0, 0, 0, 0);
            D1 = __builtin_amdgcn_mfma_f32_16x16x32_bf16(afr[1][0], b0, D1, 0, 0, 0);
            D1 = __builtin_amdgcn_mfma_f32_16x16x32_bf16(afr[1][1], b1, D1, 0, 0, 0);
            D1 = __builtin_amdgcn_mfma_f32_16x16x32_bf16(afr[1][2], b2, D1, 0, 0, 0);
            D1 = __builtin_amdgcn_mfma_f32_16x16x32_bf16(afr[1][3], b3, D1, 0, 0, 0);

            const float nmc = nmcA[ct];
            #pragma unroll
            for (int r = 0; r < 4; ++r) {
                float d0 = D0[r], d1 = D1[r];
                float e0 = EXP2(d0), e1 = EXP2(d1);
                if (DIAG) {
                    const int colg = C0 + ct * 16 + cq;
                    const float ex0 = (rbase + r == colg) ? 0.f : 1.f;
                    const float ex1 = (rbase + 16 + r == colg) ? 0.f : 1.f;
                    e0 *= ex0; d0 *= ex0;
                    e1 *= ex1; d1 *= ex1;
                }
                accE[0][r] += e0 * nmc;  cpE_[half][ct8] += e0 * nmR[0][r];
                accS[0][r] += d0 * nmc;  cpS_[half][ct8] += d0 * nmR[0][r];
                accE[1][r] += e1 * nmc;  cpE_[half][ct8] += e1 * nmR[1][r];
                accS[1][r] += d1 * nmc;  cpS_[half][ct8] += d1 * nmR[1][r];
            }
        }
        __syncthreads();   // reads done before restage / reuse
    }

    // deferred col-partial reduction (sum over the wave's 32 rows)
    #pragma unroll
    for (int hh = 0; hh < 2; ++hh)
        #pragma unroll
        for (int cc = 0; cc < 8; ++cc) {
            float e = cpE_[hh][cc], s = cpS_[hh][cc];
            e += __shfl_xor(e, 16); e += __shfl_xor(e, 32);
            s += __shfl_xor(s, 16); s += __shfl_xor(s, 32);
            if (quad == 0) {
                colE[wv][(hh * 8 + cc) * 16 + cq] = e;
                colS[wv][(hh * 8 + cc) * 16 + cq] = s;
            }
        }

    // row sums: reduce over the 16 cq lanes, write slot 2b+h
    #pragma unroll
    for (int mt = 0; mt < 2; ++mt)
        #pragma unroll
        for (int r = 0; r < 4; ++r) {
            float e = accE[mt][r], s = accS[mt][r];
            e += __shfl_xor(e, 1); e += __shfl_xor(e, 2);
            e += __shfl_xor(e, 4); e += __shfl_xor(e, 8);
            s += __shfl_xor(s, 1); s += __shfl_xor(s, 2);
            s += __shfl_xor(s, 4); s += __shfl_xor(s, 8);
            accE[mt][r] = e; accS[mt][r] = s;
        }
    if (cq == 0) {
        const size_t slotR = (size_t)(2 * b + h) * M_TOT;
        #pragma unroll
        for (int mt = 0; mt < 2; ++mt)
            #pragma unroll
            for (int r = 0; r < 4; ++r) {
                const int rowg = R0 + wv * 32 + mt * 16 + quad * 4 + r;
                rowE[slotR + rowg] = accE[mt][r];
                rowS[slotR + rowg] = accS[mt][r];
            }
    }
    // complementary slot for our rows is written by nobody -> zero it here
    {
        const size_t slotZ = (size_t)(2 * b + (1 - h)) * M_TOT;
        if (tid < 128) {
            rowE[slotZ + R0 + tid] = 0.f;
            rowS[slotZ + R0 + tid] = 0.f;
        }
    }

    __syncthreads();   // publish colE/colS
    if (!DIAG) {
        const float ce = colE[0][tid] + colE[1][tid] + colE[2][tid] + colE[3][tid];
        const float cs = colS[0][tid] + colS[1][tid] + colS[2][tid] + colS[3][tid];
        const size_t slotC = (size_t)(2 * a + h) * M_TOT;
        rowE[slotC + C0 + tid] = ce;
        rowS[slotC + C0 + tid] = cs;
    } else {
        // ---- diag-only epilogue: nf/nfpart + proto GEMM for our 128 rows ----
        if (tid == 0) {
            float c = 0.f;
            #pragma unroll
            for (int r = 0; r < 128; ++r) c += novR[r];
            nfpart[2 * a + h] = (int)c;
        }
        if (tid < 128) nf[R0 + tid] = (int)novR[tid];

        // re-stage protos into ldsB (prior ds_reads all drained by the sync)
        for (int idx = tid; idx < 3200; idx += 256) {
            const int pr = idx >> 5, sg = idx & 31;
            float4 v = ((const float4*)protos)[idx];
            *(ushort4*)&ldsB[pr * BS + sg * 4] =
                make_ushort4(f2bf(v.x), f2bf(v.y), f2bf(v.z), f2bf(v.w));
        }
        for (int idx = tid; idx < 12 * 32; idx += 256) {   // zero rows 100..111
            const int pr = B_PRO + (idx >> 5), sg = idx & 31;
            *(ushort4*)&ldsB[pr * BS + sg * 4] = make_ushort4(0, 0, 0, 0);
        }
        __syncthreads();

        float ps2[2][4], es2[2][4], pl2[2][4];
        #pragma unroll
        for (int mt = 0; mt < 2; ++mt)
            #pragma unroll
            for (int r = 0; r < 4; ++r) { ps2[mt][r] = 0.f; es2[mt][r] = 0.f; pl2[mt][r] = 0.f; }

        #pragma unroll
        for (int g = 0; g < 7; ++g) {
            const unsigned short* bp = &ldsB[(g * 16 + cq) * BS + quad * 8];
            short8 b0 = *(const short8*)(bp);
            short8 b1 = *(const short8*)(bp + 32);
            short8 b2 = *(const short8*)(bp + 64);
            short8 b3 = *(const short8*)(bp + 96);
            floatx4 E0 = (floatx4){0.f, 0.f, 0.f, 0.f};
            floatx4 E1 = (floatx4){0.f, 0.f, 0.f, 0.f};
            E0 = __builtin_amdgcn_mfma_f32_16x16x32_bf16(afr[0][0], b0, E0, 0, 0, 0);
            E0 = __builtin_amdgcn_mfma_f32_16x16x32_bf16(afr[0][1], b1, E0, 0, 0, 0);
            E0 = __builtin_amdgcn_mfma_f32_16x16x32_bf16(afr[0][2], b2, E0, 0, 0, 0);
            E0 = __builtin_amdgcn_mfma_f32_16x16x32_bf16(afr[0][3], b3, E0, 0, 0, 0);
            E1 = __builtin_amdgcn_mfma_f32_16x16x32_bf16(afr[1][0], b0, E1, 0, 0, 0);
            E1 = __builtin_amdgcn_mfma_f32_16x16x32_bf16(afr[1][1], b1, E1, 0, 0, 0);
            E1 = __builtin_amdgcn_mfma_f32_16x16x32_bf16(afr[1][2], b2, E1, 0, 0, 0);
            E1 = __builtin_amdgcn_mfma_f32_16x16x32_bf16(afr[1][3], b3, E1, 0, 0, 0);
            const int bcol = g * 16 + cq;
            if (bcol < B_PRO) {
                #pragma unroll
                for (int r = 0; r < 4; ++r) {
                    const float Pv0 = E0[r] * INV_T;
                    ps2[0][r] += Pv0; es2[0][r] += __expf(Pv0);
                    if (bcol == labRow[wv * 32 + quad * 4 + r]) pl2[0][r] += Pv0;
                    const float Pv1 = E1[r] * INV_T;
                    ps2[1][r] += Pv1; es2[1][r] += __expf(Pv1);
                    if (bcol == labRow[wv * 32 + 16 + quad * 4 + r]) pl2[1][r] += Pv1;
                }
            }
        }
        #pragma unroll
        for (int mt = 0; mt < 2; ++mt)
            #pragma unroll
            for (int r = 0; r < 4; ++r) {
                float p = ps2[mt][r], e = es2[mt][r], l = pl2[mt][r];
                p += __shfl_xor(p, 1); p += __shfl_xor(p, 2);
                p += __shfl_xor(p, 4); p += __shfl_xor(p, 8);
                e += __shfl_xor(e, 1); e += __shfl_xor(e, 2);
                e += __shfl_xor(e, 4); e += __shfl_xor(e, 8);
                l += __shfl_xor(l, 1); l += __shfl_xor(l, 2);
                l += __shfl_xor(l, 4); l += __shfl_xor(l, 8);
                if (cq == 0) {
                    const int rowg = R0 + wv * 32 + mt * 16 + quad * 4 + r;
                    Psum[rowg] = p; expPsum[rowg] = e; PLab[rowg] = l;
                }
            }
    }
}

// ---------------------------------------------------------------- k_sym
// 1056 blocks x 256 thr. Blocks 0..63: diagonal half-tiles (c = id>>1,
// h = id&1) -- these also compute the proto GEMM for their rows. Blocks
// 64..1055: strict-upper pairs (a<b), two halves each. Block 0 zeroes out[0].
__global__ __launch_bounds__(256, 3) void k_sym(
        const float* __restrict__ feat, const int* __restrict__ labels,
        const float* __restrict__ protos, const int* __restrict__ plabels,
        float* __restrict__ rowE, float* __restrict__ rowS,
        int* __restrict__ nfpart, int* __restrict__ nf,
        float* __restrict__ Psum, float* __restrict__ expPsum,
        float* __restrict__ PLab, float* __restrict__ out) {
    __shared__ unsigned short ldsB[128 * BS];    // 34816 B (reused for protos)
    __shared__ float colE[4][256];               // 4096 B
    __shared__ float colS[4][256];               // 4096 B
    __shared__ float novR[128];                  // 512 B
    __shared__ float novC[256];                  // 1024 B
    __shared__ int plabL[B_PRO];                 // 400 B
    __shared__ int labRow[128];                  // 512 B

    if (blockIdx.x == 0 && threadIdx.x == 0) out[0] = 0.f;

    const int id = blockIdx.x;
    if (id < NDIAG) {
        const int c = id >> 1, h = id & 1;
        sym_body<true>(c, c, h, c * RT + h * 128, c * RT,
                       feat, labels, protos, plabels, rowE, rowS,
                       nfpart, nf, Psum, expPsum, PLab,
                       ldsB, colE, colS, novR, novC, plabL, labRow);
    } else {
        const int tp = id - NDIAG;
        const int p = tp >> 1, h = tp & 1;
        int aa = 0, rem = p;
        while (rem >= NT - 1 - aa) { rem -= (NT - 1 - aa); ++aa; }
        const int bb2 = aa + 1 + rem;
        sym_body<false>(aa, bb2, h, aa * RT + h * 128, bb2 * RT,
                        feat, labels, protos, plabels, rowE, rowS,
                        nfpart, nf, Psum, expPsum, PLab,
                        ldsB, colE, colS, novR, novC, plabL, labRow);
    }
}

// ---------------------------------------------------------------- k_final
// 64 blocks x 128 thr, one row per thread. ep/sp = sum of the 64 rowE/rowS
// slots (coalesced across threads); everything else precomputed by k_sym.
__global__ __launch_bounds__(128) void k_final(
        const float* __restrict__ rowE, const float* __restrict__ rowS,
        const float* __restrict__ Psum, const float* __restrict__ expPsum,
        const float* __restrict__ PLab, const int* __restrict__ nf,
        const int* __restrict__ nfpart,
        float* __restrict__ out) {
    __shared__ int shNn;
    __shared__ float red[2];
    const int tid = threadIdx.x;
    const int i = blockIdx.x * 128 + tid;

    if (tid < 64) {
        int c = nfpart[tid];
        for (int off = 1; off < 64; off <<= 1) c += __shfl_xor(c, off);
        if (tid == 0) shNn = c;
    }

    float e0 = 0.f, e1 = 0.f, e2 = 0.f, e3 = 0.f;
    float s0 = 0.f, s1 = 0.f, s2 = 0.f, s3 = 0.f;
    #pragma unroll
    for (int s = 0; s < 16; ++s) {
        e0 += rowE[(size_t)(4 * s + 0) * M_TOT + i];
        e1 += rowE[(size_t)(4 * s + 1) * M_TOT + i];
        e2 += rowE[(size_t)(4 * s + 2) * M_TOT + i];
        e3 += rowE[(size_t)(4 * s + 3) * M_TOT + i];
        s0 += rowS[(size_t)(4 * s + 0) * M_TOT + i];
        s1 += rowS[(size_t)(4 * s + 1) * M_TOT + i];
        s2 += rowS[(size_t)(4 * s + 2) * M_TOT + i];
        s3 += rowS[(size_t)(4 * s + 3) * M_TOT + i];
    }
    const float ep = (e0 + e1) + (e2 + e3);
    const float sp = (s0 + s1) + (s2 + s3);

    __syncthreads();
    const int Nn = shNn;
    float contrib;
    if (nf[i]) {
        const float cnt = (float)(Nn - 1);
        const float denom = ep + Psum[i];        // + RAW proto logit sum (faithful)
        const float num = sp * LN2 - logf(denom) * cnt;
        const float sc = cnt > 0.f ? cnt : 1.f;
        contrib = -(num / sc);
    } else {
        contrib = -(PLab[i] - logf(ep + expPsum[i]));
    }
    for (int off = 1; off < 64; off <<= 1) contrib += __shfl_xor(contrib, off);
    if ((tid & 63) == 0) red[tid >> 6] = contrib;
    __syncthreads();
    if (tid == 0) atomicAdd(out, (red[0] + red[1]) * (1.0f / (float)M_TOT));
}

// ---------------------------------------------------------------- launch
extern "C" void kernel_launch(void* const* d_in, const int* in_sizes, int n_in,
                              void* d_out, int out_size, void* d_ws, size_t ws_size,
                              hipStream_t stream) {
    const float* feat    = (const float*)d_in[0];
    const int*   labels  = (const int*)d_in[1];
    const float* protos  = (const float*)d_in[2];
    const int*   plabels = (const int*)d_in[3];
    float* out = (float*)d_out;

    char* ws = (char*)d_ws;
    float* rowE    = (float*)ws;                     // 64 x 8192 fp32 (2 MB)
    float* rowS    = (float*)(ws + 2097152);         // 64 x 8192 fp32 (2 MB)
    int*   nfpart  = (int*)(ws + 4194304);           // 64 ints
    int*   nf      = (int*)(ws + 4194560);           // 8192 ints
    float* Psum    = (float*)(ws + 4227328);
    float* expPsum = (float*)(ws + 4260096);
    float* PLab    = (float*)(ws + 4292864);

    k_sym<<<NBLK, 256, 0, stream>>>(feat, labels, protos, plabels,
                                    rowE, rowS, nfpart, nf,
                                    Psum, expPsum, PLab, out);
    k_final<<<64, 128, 0, stream>>>(rowE, rowS, Psum, expPsum, PLab,
                                    nf, nfpart, out);
}

// Round 6
// 100.016 us; speedup vs baseline: 2.0063x; 2.0063x over previous
//
#include <hip/hip_runtime.h>
#include <stdint.h>

// SupConLossWithPrototype on MI355X.
// Round 17: recover from the round-16 spill regression (WRITE_SIZE 172MB =
// scratch traffic from cp-register arrays + full unroll + extended afr
// liveness). This round:
//  - inner loop reverted to the round-15-proven body (per-ct shfl+LDS col
//    partial, unroll-1 phase loop; 84 VGPR, no spill).
//  - tiles merged to full 256x256 / 512-thread blocks (528 blocks, 2/CU,
//    launch_bounds(512,4) -> 128 VGPR cap): B staged+converted once per
//    block (was twice), 32 slots/row (was 64), no complementary-slot
//    zeroing (every slot written exactly once by construction).
//  - diag blocks keep the proto GEMM epilogue (reuse afr; path-local
//    pressure ~90 < 128). k_final stays tiny: 64 x 128.

#define M_TOT 8192
#define K_DIM 128
#define B_PRO 100
#define INV_T 5.0f                          // 1/TEMP
#define C_SCALE 7.2134752044448170f         // 5 * log2(e)
#define LN2    0.6931471805599453f
#define RT    256                           // tile side
#define NT    (M_TOT / RT)                  // 32 row/col groups
#define NPAIR (NT * (NT - 1) / 2)           // 496 strict upper pairs
#define NBLK  (NT + NPAIR)                  // 528 blocks
#define BS    136                           // B/proto LDS stride (bf16 elems)
#define PB    112                           // padded proto rows (7 groups of 16)

#if __has_builtin(__builtin_amdgcn_exp2f)
#define EXP2(x) __builtin_amdgcn_exp2f(x)
#else
#define EXP2(x) __expf((x) * 0.6931471805599453f)
#endif

typedef __attribute__((ext_vector_type(8))) short  short8;   // 8 bf16 (MFMA A/B frag)
typedef __attribute__((ext_vector_type(4))) float  floatx4;  // MFMA C/D frag

__device__ __forceinline__ unsigned short f2bf(float x) {   // RNE
    union { float f; unsigned int i; } v; v.f = x;
    return (unsigned short)((v.i + 0x7fffu + ((v.i >> 16) & 1u)) >> 16);
}
__device__ __forceinline__ short8 pack8(float4 a, float4 b) {
    short8 r;
    r[0] = (short)f2bf(a.x); r[1] = (short)f2bf(a.y);
    r[2] = (short)f2bf(a.z); r[3] = (short)f2bf(a.w);
    r[4] = (short)f2bf(b.x); r[5] = (short)f2bf(b.y);
    r[6] = (short)f2bf(b.z); r[7] = (short)f2bf(b.w);
    return r;
}

// ---------------------------------------------------------------- k_sym body
// One 256x256 tile, 512 threads (8 waves x 32 rows). Operands converted
// in-block from f32 feat; B staged to LDS bf16(C*f) in two 128-col phases.
// Dual accumulation: accE = sum exp2(D)*mask, accS = sum D*mask, row and col
// direction. DIAG excludes row==col exactly and afterwards computes the
// proto GEMM for its 256 rows (reusing afr + ldsB).
// Slot coverage (32 slots/row): row i in group g gets slot s from tile (g,s)
// row-side for s>=g and from tile (s,g) col-side for s<g -> exactly once.
template<bool DIAG>
__device__ __forceinline__ void sym_body(
        int a, int b, int R0, int C0,
        const float* __restrict__ feat, const int* __restrict__ labels,
        const float* __restrict__ protos, const int* __restrict__ plabels,
        float* __restrict__ rowE, float* __restrict__ rowS,
        int* __restrict__ nfpart, int* __restrict__ nf,
        float* __restrict__ Psum, float* __restrict__ expPsum,
        float* __restrict__ PLab,
        unsigned short* ldsB, float (*colE)[256], float (*colS)[256],
        float* novR, float* novC, int* plabL, int* labRow, float* redD) {
    const int tid = threadIdx.x;            // 0..511
    const int wv = tid >> 6, lane = tid & 63;
    const int quad = lane >> 4, cq = lane & 15;

    if (tid < B_PRO) plabL[tid] = plabels[tid];

    // A fragments straight from f32 feat, converted in registers:
    // rows R0 + wv*32 + mt*16 + cq, k = ks*32 + quad*8 .. +7
    short8 afr[2][4];
    #pragma unroll
    for (int mt = 0; mt < 2; ++mt)
        #pragma unroll
        for (int ks = 0; ks < 4; ++ks) {
            const float* s = feat + (size_t)(R0 + wv * 32 + mt * 16 + cq) * K_DIM
                             + ks * 32 + quad * 8;
            float4 x = ((const float4*)s)[0];
            float4 y = ((const float4*)s)[1];
            afr[mt][ks] = pack8(x, y);
        }
    __syncthreads();   // plabL visible

    // novelty: 256 rows + 256 cols, one entry per thread
    {
        const int g = (tid < 256) ? (R0 + tid) : (C0 + (tid - 256));
        const int lbl = labels[g];
        int m = 0;
        #pragma unroll 4
        for (int j = 0; j < B_PRO; ++j) m |= (plabL[j] == lbl);
        const float nv = m ? 0.f : 1.f;
        if (tid < 256) { novR[tid] = nv; labRow[tid] = lbl; }
        else novC[tid - 256] = nv;
    }
    __syncthreads();   // novR/novC visible

    float nmR[2][4];
    #pragma unroll
    for (int mt = 0; mt < 2; ++mt)
        #pragma unroll
        for (int r = 0; r < 4; ++r)
            nmR[mt][r] = novR[wv * 32 + mt * 16 + quad * 4 + r];
    float nmcA[16];
    #pragma unroll
    for (int c2 = 0; c2 < 16; ++c2)
        nmcA[c2] = novC[c2 * 16 + cq];

    float accE[2][4], accS[2][4];
    #pragma unroll
    for (int mt = 0; mt < 2; ++mt)
        #pragma unroll
        for (int r = 0; r < 4; ++r) { accE[mt][r] = 0.f; accS[mt][r] = 0.f; }

    const int rbase = R0 + wv * 32 + quad * 4;   // DIAG row index helper

    #pragma unroll 1
    for (int half = 0; half < 2; ++half) {
        // stage cols [C0 + half*128, +128) as bf16(C*f) into LDS (4/thread)
        for (int e = tid; e < 2048; e += 512) {
            const int col = e >> 4, sg = e & 15;
            const float* s = feat + (size_t)(C0 + half * 128 + col) * K_DIM + sg * 8;
            float4 x = ((const float4*)s)[0];
            float4 y = ((const float4*)s)[1];
            ushort4 o0 = make_ushort4(f2bf(x.x*C_SCALE), f2bf(x.y*C_SCALE),
                                      f2bf(x.z*C_SCALE), f2bf(x.w*C_SCALE));
            ushort4 o1 = make_ushort4(f2bf(y.x*C_SCALE), f2bf(y.y*C_SCALE),
                                      f2bf(y.z*C_SCALE), f2bf(y.w*C_SCALE));
            *(ushort4*)&ldsB[col * BS + sg * 8]     = o0;
            *(ushort4*)&ldsB[col * BS + sg * 8 + 4] = o1;
        }
        __syncthreads();   // staging visible

        #pragma unroll 2
        for (int ct8 = 0; ct8 < 8; ++ct8) {
            const int ct = half * 8 + ct8;
            const unsigned short* bp = &ldsB[(ct8 * 16 + cq) * BS + quad * 8];
            short8 b0 = *(const short8*)(bp);
            short8 b1 = *(const short8*)(bp + 32);
            short8 b2 = *(const short8*)(bp + 64);
            short8 b3 = *(const short8*)(bp + 96);

            floatx4 D0 = (floatx4){0.f, 0.f, 0.f, 0.f};
            floatx4 D1 = (floatx4){0.f, 0.f, 0.f, 0.f};
            D0 = __builtin_amdgcn_mfma_f32_16x16x32_bf16(afr[0][0], b0, D0, 0, 0, 0);
            D0 = __builtin_amdgcn_mfma_f32_16x16x32_bf16(afr[0][1], b1, D0, 0, 0, 0);
            D0 = __builtin_amdgcn_mfma_f32_16x16x32_bf16(afr[0][2], b2, D0, 0, 0, 0);
            D0 = __builtin_amdgcn_mfma_f32_16x16x32_bf16(afr[0][3], b3, D0, 0, 0, 0);
            D1 = __builtin_amdgcn_mfma_f32_16x16x32_bf16(afr[1][0], b0, D1, 0, 0, 0);
            D1 = __builtin_amdgcn_mfma_f32_16x16x32_bf16(afr[1][1], b1, D1, 0, 0, 0);
            D1 = __builtin_amdgcn_mfma_f32_16x16x32_bf16(afr[1][2], b2, D1, 0, 0, 0);
            D1 = __builtin_amdgcn_mfma_f32_16x16x32_bf16(afr[1][3], b3, D1, 0, 0, 0);

            const float nmc = nmcA[ct];
            float cpE = 0.f, cpS = 0.f;
            #pragma unroll
            for (int r = 0; r < 4; ++r) {
                float d0 = D0[r], d1 = D1[r];
                float e0 = EXP2(d0), e1 = EXP2(d1);
                if (DIAG) {
                    const int colg = C0 + ct * 16 + cq;
                    const float ex0 = (rbase + r == colg) ? 0.f : 1.f;
                    const float ex1 = (rbase + 16 + r == colg) ? 0.f : 1.f;
                    e0 *= ex0; d0 *= ex0;
                    e1 *= ex1; d1 *= ex1;
                }
                accE[0][r] += e0 * nmc;  cpE += e0 * nmR[0][r];
                accS[0][r] += d0 * nmc;  cpS += d0 * nmR[0][r];
                accE[1][r] += e1 * nmc;  cpE += e1 * nmR[1][r];
                accS[1][r] += d1 * nmc;  cpS += d1 * nmR[1][r];
            }
            cpE += __shfl_xor(cpE, 16); cpE += __shfl_xor(cpE, 32);
            cpS += __shfl_xor(cpS, 16); cpS += __shfl_xor(cpS, 32);
            if (quad == 0) {
                colE[wv][ct * 16 + cq] = cpE;
                colS[wv][ct * 16 + cq] = cpS;
            }
        }
        __syncthreads();   // reads done before restage; publishes colE/colS
    }

    // row sums: reduce over the 16 cq lanes, write slot b
    #pragma unroll
    for (int mt = 0; mt < 2; ++mt)
        #pragma unroll
        for (int r = 0; r < 4; ++r) {
            float e = accE[mt][r], s = accS[mt][r];
            e += __shfl_xor(e, 1); e += __shfl_xor(e, 2);
            e += __shfl_xor(e, 4); e += __shfl_xor(e, 8);
            s += __shfl_xor(s, 1); s += __shfl_xor(s, 2);
            s += __shfl_xor(s, 4); s += __shfl_xor(s, 8);
            accE[mt][r] = e; accS[mt][r] = s;
        }
    if (cq == 0) {
        const size_t slotR = (size_t)b * M_TOT;
        #pragma unroll
        for (int mt = 0; mt < 2; ++mt)
            #pragma unroll
            for (int r = 0; r < 4; ++r) {
                const int rowg = R0 + wv * 32 + mt * 16 + quad * 4 + r;
                rowE[slotR + rowg] = accE[mt][r];
                rowS[slotR + rowg] = accS[mt][r];
            }
    }

    if (!DIAG) {
        // col side -> slot a (colE/colS published by the half-loop-end sync)
        if (tid < 256) {
            float ce = 0.f, cs = 0.f;
            #pragma unroll
            for (int w = 0; w < 8; ++w) { ce += colE[w][tid]; cs += colS[w][tid]; }
            const size_t slotC = (size_t)a * M_TOT;
            rowE[slotC + C0 + tid] = ce;
            rowS[slotC + C0 + tid] = cs;
        }
    } else {
        // ---- diag-only epilogue: nf/nfpart + proto GEMM for our 256 rows ----
        {
            float nvv = (tid < 256) ? novR[tid] : 0.f;
            for (int off = 1; off < 64; off <<= 1) nvv += __shfl_xor(nvv, off);
            if (lane == 0) redD[wv] = nvv;
        }
        if (tid < 256) nf[R0 + tid] = (int)novR[tid];

        // re-stage protos into ldsB (main-loop reads drained by the last sync)
        for (int idx = tid; idx < 3200; idx += 512) {
            const int pr = idx >> 5, sg = idx & 31;
            float4 v = ((const float4*)protos)[idx];
            *(ushort4*)&ldsB[pr * BS + sg * 4] =
                make_ushort4(f2bf(v.x), f2bf(v.y), f2bf(v.z), f2bf(v.w));
        }
        for (int idx = tid; idx < 384; idx += 512) {   // zero rows 100..111
            const int pr = B_PRO + (idx >> 5), sg = idx & 31;
            *(ushort4*)&ldsB[pr * BS + sg * 4] = make_ushort4(0, 0, 0, 0);
        }
        __syncthreads();

        if (tid == 0) {
            float c = 0.f;
            #pragma unroll
            for (int w = 0; w < 8; ++w) c += redD[w];
            nfpart[a] = (int)c;
        }

        float ps2[2][4], es2[2][4], pl2[2][4];
        #pragma unroll
        for (int mt = 0; mt < 2; ++mt)
            #pragma unroll
            for (int r = 0; r < 4; ++r) { ps2[mt][r]=0.f; es2[mt][r]=0.f; pl2[mt][r]=0.f; }

        #pragma unroll 1
        for (int g = 0; g < 7; ++g) {
            const unsigned short* bp = &ldsB[(g * 16 + cq) * BS + quad * 8];
            short8 b0 = *(const short8*)(bp);
            short8 b1 = *(const short8*)(bp + 32);
            short8 b2 = *(const short8*)(bp + 64);
            short8 b3 = *(const short8*)(bp + 96);
            floatx4 E0 = (floatx4){0.f, 0.f, 0.f, 0.f};
            floatx4 E1 = (floatx4){0.f, 0.f, 0.f, 0.f};
            E0 = __builtin_amdgcn_mfma_f32_16x16x32_bf16(afr[0][0], b0, E0, 0, 0, 0);
            E0 = __builtin_amdgcn_mfma_f32_16x16x32_bf16(afr[0][1], b1, E0, 0, 0, 0);
            E0 = __builtin_amdgcn_mfma_f32_16x16x32_bf16(afr[0][2], b2, E0, 0, 0, 0);
            E0 = __builtin_amdgcn_mfma_f32_16x16x32_bf16(afr[0][3], b3, E0, 0, 0, 0);
            E1 = __builtin_amdgcn_mfma_f32_16x16x32_bf16(afr[1][0], b0, E1, 0, 0, 0);
            E1 = __builtin_amdgcn_mfma_f32_16x16x32_bf16(afr[1][1], b1, E1, 0, 0, 0);
            E1 = __builtin_amdgcn_mfma_f32_16x16x32_bf16(afr[1][2], b2, E1, 0, 0, 0);
            E1 = __builtin_amdgcn_mfma_f32_16x16x32_bf16(afr[1][3], b3, E1, 0, 0, 0);
            const int bcol = g * 16 + cq;
            if (bcol < B_PRO) {
                #pragma unroll
                for (int r = 0; r < 4; ++r) {
                    const float Pv0 = E0[r] * INV_T;
                    ps2[0][r] += Pv0; es2[0][r] += __expf(Pv0);
                    if (bcol == labRow[wv * 32 + quad * 4 + r]) pl2[0][r] += Pv0;
                    const float Pv1 = E1[r] * INV_T;
                    ps2[1][r] += Pv1; es2[1][r] += __expf(Pv1);
                    if (bcol == labRow[wv * 32 + 16 + quad * 4 + r]) pl2[1][r] += Pv1;
                }
            }
        }
        #pragma unroll
        for (int mt = 0; mt < 2; ++mt)
            #pragma unroll
            for (int r = 0; r < 4; ++r) {
                float p = ps2[mt][r], e = es2[mt][r], l = pl2[mt][r];
                p += __shfl_xor(p, 1); p += __shfl_xor(p, 2);
                p += __shfl_xor(p, 4); p += __shfl_xor(p, 8);
                e += __shfl_xor(e, 1); e += __shfl_xor(e, 2);
                e += __shfl_xor(e, 4); e += __shfl_xor(e, 8);
                l += __shfl_xor(l, 1); l += __shfl_xor(l, 2);
                l += __shfl_xor(l, 4); l += __shfl_xor(l, 8);
                if (cq == 0) {
                    const int rowg = R0 + wv * 32 + mt * 16 + quad * 4 + r;
                    Psum[rowg] = p; expPsum[rowg] = e; PLab[rowg] = l;
                }
            }
    }
}

// ---------------------------------------------------------------- k_sym
// 528 blocks x 512 thr. Blocks 0..31: diagonal tiles (also proto GEMM for
// their 256 rows). Blocks 32..527: strict-upper pairs. Block 0 zeroes out[0].
__global__ __launch_bounds__(512, 4) void k_sym(
        const float* __restrict__ feat, const int* __restrict__ labels,
        const float* __restrict__ protos, const int* __restrict__ plabels,
        float* __restrict__ rowE, float* __restrict__ rowS,
        int* __restrict__ nfpart, int* __restrict__ nf,
        float* __restrict__ Psum, float* __restrict__ expPsum,
        float* __restrict__ PLab, float* __restrict__ out) {
    __shared__ unsigned short ldsB[128 * BS];    // 34816 B (reused for protos)
    __shared__ float colE[8][256];               // 8192 B
    __shared__ float colS[8][256];               // 8192 B
    __shared__ float novR[256];                  // 1024 B
    __shared__ float novC[256];                  // 1024 B
    __shared__ int plabL[B_PRO];                 // 400 B
    __shared__ int labRow[256];                  // 1024 B
    __shared__ float redD[8];                    // 32 B

    if (blockIdx.x == 0 && threadIdx.x == 0) out[0] = 0.f;

    const int id = blockIdx.x;
    if (id < NT) {
        sym_body<true>(id, id, id * RT, id * RT,
                       feat, labels, protos, plabels, rowE, rowS,
                       nfpart, nf, Psum, expPsum, PLab,
                       ldsB, colE, colS, novR, novC, plabL, labRow, redD);
    } else {
        const int p = id - NT;
        int aa = 0, rem = p;
        while (rem >= NT - 1 - aa) { rem -= (NT - 1 - aa); ++aa; }
        const int bb2 = aa + 1 + rem;
        sym_body<false>(aa, bb2, aa * RT, bb2 * RT,
                        feat, labels, protos, plabels, rowE, rowS,
                        nfpart, nf, Psum, expPsum, PLab,
                        ldsB, colE, colS, novR, novC, plabL, labRow, redD);
    }
}

// ---------------------------------------------------------------- k_final
// 64 blocks x 128 thr, one row per thread. ep/sp = sum of the 32 rowE/rowS
// slots (slot-major -> coalesced); everything else precomputed by k_sym.
__global__ __launch_bounds__(128) void k_final(
        const float* __restrict__ rowE, const float* __restrict__ rowS,
        const float* __restrict__ Psum, const float* __restrict__ expPsum,
        const float* __restrict__ PLab, const int* __restrict__ nf,
        const int* __restrict__ nfpart,
        float* __restrict__ out) {
    __shared__ int shNn;
    __shared__ float red[2];
    const int tid = threadIdx.x;
    const int i = blockIdx.x * 128 + tid;

    if (tid < 32) {
        int c = nfpart[tid];
        for (int off = 1; off < 32; off <<= 1) c += __shfl_xor(c, off);
        if (tid == 0) shNn = c;
    }

    float e0 = 0.f, e1 = 0.f, e2 = 0.f, e3 = 0.f;
    float s0 = 0.f, s1 = 0.f, s2 = 0.f, s3 = 0.f;
    #pragma unroll
    for (int s = 0; s < 8; ++s) {
        e0 += rowE[(size_t)(4 * s + 0) * M_TOT + i];
        e1 += rowE[(size_t)(4 * s + 1) * M_TOT + i];
        e2 += rowE[(size_t)(4 * s + 2) * M_TOT + i];
        e3 += rowE[(size_t)(4 * s + 3) * M_TOT + i];
        s0 += rowS[(size_t)(4 * s + 0) * M_TOT + i];
        s1 += rowS[(size_t)(4 * s + 1) * M_TOT + i];
        s2 += rowS[(size_t)(4 * s + 2) * M_TOT + i];
        s3 += rowS[(size_t)(4 * s + 3) * M_TOT + i];
    }
    const float ep = (e0 + e1) + (e2 + e3);
    const float sp = (s0 + s1) + (s2 + s3);

    __syncthreads();
    const int Nn = shNn;
    float contrib;
    if (nf[i]) {
        const float cnt = (float)(Nn - 1);
        const float denom = ep + Psum[i];        // + RAW proto logit sum (faithful)
        const float num = sp * LN2 - logf(denom) * cnt;
        const float sc = cnt > 0.f ? cnt : 1.f;
        contrib = -(num / sc);
    } else {
        contrib = -(PLab[i] - logf(ep + expPsum[i]));
    }
    for (int off = 1; off < 64; off <<= 1) contrib += __shfl_xor(contrib, off);
    if ((tid & 63) == 0) red[tid >> 6] = contrib;
    __syncthreads();
    if (tid == 0) atomicAdd(out, (red[0] + red[1]) * (1.0f / (float)M_TOT));
}

// ---------------------------------------------------------------- launch
extern "C" void kernel_launch(void* const* d_in, const int* in_sizes, int n_in,
                              void* d_out, int out_size, void* d_ws, size_t ws_size,
                              hipStream_t stream) {
    const float* feat    = (const float*)d_in[0];
    const int*   labels  = (const int*)d_in[1];
    const float* protos  = (const float*)d_in[2];
    const int*   plabels = (const int*)d_in[3];
    float* out = (float*)d_out;

    char* ws = (char*)d_ws;
    float* rowE    = (float*)ws;                     // 32 x 8192 fp32 (1 MB)
    float* rowS    = (float*)(ws + 1048576);         // 32 x 8192 fp32 (1 MB)
    int*   nfpart  = (int*)(ws + 2097152);           // 32 ints
    int*   nf      = (int*)(ws + 2101248);           // 8192 ints
    float* Psum    = (float*)(ws + 2134016);
    float* expPsum = (float*)(ws + 2166784);
    float* PLab    = (float*)(ws + 2199552);

    k_sym<<<NBLK, 512, 0, stream>>>(feat, labels, protos, plabels,
                                    rowE, rowS, nfpart, nf,
                                    Psum, expPsum, PLab, out);
    k_final<<<64, 128, 0, stream>>>(rowE, rowS, Psum, expPsum, PLab,
                                    nf, nfpart, out);
}